// Round 9
// baseline (1139.750 us; speedup 1.0000x reference)
//
#include <hip/hip_runtime.h>
#include <hip/hip_bf16.h>

// ---------------- problem constants ----------------
#define NN 500000
#define EE 1250000
#define NP 501760          // padded node count
#define NBLK 489           // scan blocks of 1024
#define GCAP 16384         // nlist capacity per graph (expected 7812, 2.1x margin)

typedef __attribute__((ext_vector_type(8))) short bf16x8;
typedef __attribute__((ext_vector_type(4))) float f32x4;

__device__ __forceinline__ float ngnn97_bf2f(unsigned short u) {
  return __uint_as_float(((unsigned int)u) << 16);
}
__device__ __forceinline__ unsigned short ngnn97_f2bf(float f) {
  union { __hip_bfloat16 b; unsigned short u; } cv;
  cv.b = __float2bfloat16(f);
  return cv.u;
}
// accumulate 4 dwords (8 bf16) into lo/hi f32 accumulators, dword-wise
__device__ __forceinline__ void ngnn97_acc8(uint4 u, float* lo, float* hi) {
  lo[0] += __uint_as_float(u.x << 16); hi[0] += __uint_as_float(u.x & 0xFFFF0000u);
  lo[1] += __uint_as_float(u.y << 16); hi[1] += __uint_as_float(u.y & 0xFFFF0000u);
  lo[2] += __uint_as_float(u.z << 16); hi[2] += __uint_as_float(u.z & 0xFFFF0000u);
  lo[3] += __uint_as_float(u.w << 16); hi[3] += __uint_as_float(u.w & 0xFFFF0000u);
}

// ---------------- diagnostic code writer (guard path only) ----------------
__global__ void ngnn97_code(float* __restrict__ out, float v) {
  if (threadIdx.x < 64) out[threadIdx.x] = v;
}

// ---------------- precompute folded weights (bf16, MFMA-B layout) + bf16 ztab ----------------
__global__ __launch_bounds__(256) void ngnn97_pre(
    const float* __restrict__ ggc, const float* __restrict__ wih,
    const float* __restrict__ whh, const float* __restrict__ bih,
    const float* __restrict__ bhh, const float* __restrict__ tfW,
    const float* __restrict__ ztab,
    unsigned short* __restrict__ Ubt, float* __restrict__ Ub,
    unsigned short* __restrict__ Vbt, unsigned short* __restrict__ ztabh) {
  int idx = blockIdx.x * 256 + threadIdx.x;
  if (idx < 163840) {                      // Ubt: 5*256*128
    int l = idx >> 15, r = idx & 32767;
    int n = r >> 7, k = r & 127;
    float v = 0.f;
    if (k < 64) {
      if (n < 192) {
        const float* gp = ggc + l * 4096 + k * 64;
        const float* wp = wih + l * 12288 + n * 64;
        float acc = 0.f;
#pragma unroll
        for (int t2 = 0; t2 < 64; t2++) acc = fmaf(gp[t2], wp[t2], acc);
        v = acc;
      }
    } else {
      int k2 = k - 64;
      if (n < 128) v = whh[l * 12288 + n * 64 + k2];
      else if (n >= 192) v = whh[l * 12288 + (n - 64) * 64 + k2];
    }
    Ubt[idx] = ngnn97_f2bf(v);
  } else if (idx < 196608) {               // Vbt: 4*64*128 (= tfW flat)
    int i2 = idx - 163840;
    Vbt[i2] = ngnn97_f2bf(tfW[i2]);
  } else if (idx < 197888) {               // Ub: 5*256
    int i2 = idx - 196608;
    int l = i2 >> 8, j = i2 & 255;
    float v;
    if (j < 128)      v = bih[l * 192 + j] + bhh[l * 192 + j];
    else if (j < 192) v = bih[l * 192 + j];
    else              v = bhh[l * 192 + j - 64];
    Ub[i2] = v;
  } else if (idx < 229888) {               // ztabh: 5*100*64 bf16
    int i2 = idx - 197888;
    ztabh[i2] = ngnn97_f2bf(ztab[i2]);
  }
}

// ---------------- CSR build ----------------
__global__ __launch_bounds__(256) void ngnn97_hist(const int* __restrict__ dst, int* __restrict__ counts) {
  int e = blockIdx.x * 256 + threadIdx.x;
  if (e < EE) atomicAdd(&counts[dst[e]], 1);
}

__global__ __launch_bounds__(256) void ngnn97_red(const int* __restrict__ counts, int* __restrict__ bsum) {
  __shared__ int s[256];
  int t = threadIdx.x, base = blockIdx.x * 1024;
  int v = 0;
#pragma unroll
  for (int i = 0; i < 4; i++) v += counts[base + t + i * 256];
  s[t] = v; __syncthreads();
  for (int o = 128; o > 0; o >>= 1) { if (t < o) s[t] += s[t + o]; __syncthreads(); }
  if (t == 0) bsum[blockIdx.x] = s[0];
}

__global__ __launch_bounds__(512) void ngnn97_scan1(const int* __restrict__ bsum, int* __restrict__ boff) {
  __shared__ int s[512];
  int t = threadIdx.x;
  int v = (t < NBLK) ? bsum[t] : 0;
  s[t] = v; __syncthreads();
  for (int o = 1; o < 512; o <<= 1) {
    int a = (t >= o) ? s[t - o] : 0;
    __syncthreads(); s[t] += a; __syncthreads();
  }
  if (t < NBLK) boff[t] = s[t] - v;   // exclusive
}

__global__ __launch_bounds__(256) void ngnn97_scan2(const int* __restrict__ counts, const int* __restrict__ boff,
                                                    int* __restrict__ row_ptr, int* __restrict__ cursor) {
  __shared__ int s[256];
  int t = threadIdx.x, base = blockIdx.x * 1024;
  int4 c = *(const int4*)(counts + base + t * 4);
  int tsum = c.x + c.y + c.z + c.w;
  s[t] = tsum; __syncthreads();
  for (int o = 1; o < 256; o <<= 1) {
    int a = (t >= o) ? s[t - o] : 0;
    __syncthreads(); s[t] += a; __syncthreads();
  }
  int off = boff[blockIdx.x] + s[t] - tsum;
  int4 r;
  r.x = off; r.y = off + c.x; r.z = off + c.x + c.y; r.w = off + c.x + c.y + c.z;
  *(int4*)(row_ptr + base + t * 4) = r;
  *(int4*)(cursor + base + t * 4) = r;
}

__global__ __launch_bounds__(256) void ngnn97_fill(const int* __restrict__ src, const int* __restrict__ dst,
                                                   int* __restrict__ cursor, int* __restrict__ srcs) {
  int e = blockIdx.x * 256 + threadIdx.x;
  if (e < EE) {
    int pos = atomicAdd(&cursor[dst[e]], 1);
    srcs[pos] = src[e];
  }
}

// ---------------- node -> graph id precompute (uint8) ----------------
__global__ __launch_bounds__(256) void ngnn97_g8(const int* __restrict__ n2s, const int* __restrict__ s2g,
                                                 unsigned char* __restrict__ g8) {
  int idx = blockIdx.x * 256 + threadIdx.x;
  if (idx < NN) g8[idx] = (unsigned char)s2g[n2s[idx]];
}

// ---------------- bucket nodes by graph: LDS hist + two-pass fill ----------------
__global__ __launch_bounds__(256) void ngnn97_bucket(const unsigned char* __restrict__ g8,
                                                     int* __restrict__ gcur, int* __restrict__ nlist) {
  __shared__ int hcnt[64];
  __shared__ int hbase[64];
  int t = threadIdx.x;
  int base = blockIdx.x * 1024;
  if (t < 64) hcnt[t] = 0;
  __syncthreads();
#pragma unroll
  for (int i = 0; i < 4; i++) {
    int node = base + i * 256 + t;
    if (node < NN) atomicAdd(&hcnt[g8[node]], 1);
  }
  __syncthreads();
  if (t < 64) {
    int c = hcnt[t];
    hbase[t] = (c > 0) ? atomicAdd(&gcur[t], c) : 0;
    hcnt[t] = 0;
  }
  __syncthreads();
#pragma unroll
  for (int i = 0; i < 4; i++) {
    int node = base + i * 256 + t;
    if (node < NN) {
      int g = g8[node];
      int loc = atomicAdd(&hcnt[g], 1);
      int pos = hbase[g] + loc;
      if (pos < GCAP) nlist[g * GCAP + pos] = node;
    }
  }
}

// ---------------- SEGMENT-LOCAL degree sort (counting sort per 1024 nodes) ----------------
// Wave-degree uniformity (waves get contiguous degree ranges) WITHOUT destroying
// xh locality: each segment's perm entries stay within a 128 KB xh window.
__global__ __launch_bounds__(256) void ngnn97_dsort(const int* __restrict__ rowp,
                                                    int* __restrict__ perm) {
  __shared__ int hcnt[64];
  __shared__ int hoff[64];
  int t = threadIdx.x, base = blockIdx.x * 1024;
  if (t < 64) hcnt[t] = 0;
  __syncthreads();
#pragma unroll
  for (int i = 0; i < 4; i++) {
    int node = base + i * 256 + t;
    if (node < NN) {
      int d = rowp[node + 1] - rowp[node];
      if (d > 63) d = 63;
      atomicAdd(&hcnt[d], 1);
    }
  }
  __syncthreads();
  if (t == 0) {                      // tiny serial scan over 64 bins (one-time kernel)
    int s = 0;
    for (int d = 0; d < 64; d++) { hoff[d] = s; s += hcnt[d]; }
  }
  __syncthreads();
  if (t < 64) hcnt[t] = 0;
  __syncthreads();
#pragma unroll
  for (int i = 0; i < 4; i++) {
    int node = base + i * 256 + t;
    if (node < NN) {
      int d = rowp[node + 1] - rowp[node];
      if (d > 63) d = 63;
      int loc = atomicAdd(&hcnt[d], 1);
      perm[base + hoff[d] + loc] = node;
    }
  }
}

// ---------------- layer-0 embedding: bf16x8 row copies from ztabh ----------------
__global__ __launch_bounds__(256) void ngnn97_embed(const int* __restrict__ z,
                                                    const unsigned short* __restrict__ ztabh,
                                                    unsigned short* __restrict__ xh) {
  int idx = blockIdx.x * 256 + threadIdx.x;
  int node = idx >> 3, sub = idx & 7;
  if (node < NN) {
    int zz = z[node];
    *(bf16x8*)(xh + (size_t)node * 64 + sub * 8) =
        *(const bf16x8*)(ztabh + zz * 64 + sub * 8);
  }
}

// ---------------- FUSED gather + GRU via MFMA (+ optional transform) ----------------
// r7-proven structure (1066 us): 1-wave blocks (64 thr, 32 permuted nodes), zero
// barriers, 4.7 KB LDS, no launch-bounds squeeze (natural ~60-62 VGPR -> 4 waves/SIMD;
// wg-slot limit also caps at 4 -> both constraints agree, occupancy lever closed).
// NEW: srcs pair-PREFETCH (guard-free: srcs padded +2 ints) -> gather loop critical
// path drops from srcs-load->row-load (2 latencies) to row-load only.
__global__ __launch_bounds__(64, 4) void ngnn97_gru(
    const unsigned short* __restrict__ xh_old, unsigned short* __restrict__ xh_new,
    const int* __restrict__ rowp, const int* __restrict__ srcs,
    const int* __restrict__ perm,
    const unsigned short* __restrict__ Ubt, const float* __restrict__ Ub,
    const unsigned short* __restrict__ Vbt, const float* __restrict__ tfb,
    const int* __restrict__ z, const unsigned short* __restrict__ ztabh,
    int do_transform) {
  __shared__ unsigned short Abuf[32 * 72];     // 4.6 KB: agg -> xh -> xn scratch
  __shared__ int pnode[32];
  const int lane = threadIdx.x;                // 1 wave
  const int ncol = lane & 15, quad = lane >> 4;
  const int nbase = blockIdx.x * 32;

  if (lane < 32) {
    int idx = nbase + lane;
    pnode[lane] = (idx < NN) ? perm[idx] : NN;  // sentinel NN = inactive row
  }
  // same-wave DS ordering: all later reads see these writes

  // ---- gather: 2 sub-batches x 16 rows, 4 lanes (sub) per row -> Abuf cols 0..63 ----
  {
    int grp = lane >> 2, sub = lane & 3;       // grp 0..15; sub owns elems [sub*16,+16)
#pragma unroll
    for (int sb = 0; sb < 2; sb++) {
      int row = sb * 16 + grp;
      int node = pnode[row];
      float lo[8], hi[8];
#pragma unroll
      for (int i = 0; i < 8; i++) { lo[i] = 0.f; hi[i] = 0.f; }
      if (node < NN) {
        int b = rowp[node], e = rowp[node + 1];
        int p = b;
        if (p + 2 <= e) {
          int s0 = srcs[p], s1 = srcs[p + 1];
          for (; p + 2 <= e; p += 2) {
            int n0 = srcs[p + 2];              // guard-free prefetch (srcs padded +2):
            int n1 = srcs[p + 3];              // next pair in flight during row loads
            const unsigned short* r0 = xh_old + (size_t)s0 * 64 + sub * 16;
            const unsigned short* r1 = xh_old + (size_t)s1 * 64 + sub * 16;
            uint4 u0 = *(const uint4*)(r0);
            uint4 u1 = *(const uint4*)(r0 + 8);
            uint4 u2 = *(const uint4*)(r1);
            uint4 u3 = *(const uint4*)(r1 + 8);
            ngnn97_acc8(u0, lo, hi); ngnn97_acc8(u1, lo + 4, hi + 4);
            ngnn97_acc8(u2, lo, hi); ngnn97_acc8(u3, lo + 4, hi + 4);
            s0 = n0; s1 = n1;
          }
        }
        if (p < e) {                           // odd tail (srcs[p] is L1-hot)
          const unsigned short* r0 = xh_old + (size_t)srcs[p] * 64 + sub * 16;
          uint4 u0 = *(const uint4*)(r0);
          uint4 u1 = *(const uint4*)(r0 + 8);
          ngnn97_acc8(u0, lo, hi);
          ngnn97_acc8(u1, lo + 4, hi + 4);
        }
      }
      // pack: dword j of chunk c -> elements (c*8+2j, c*8+2j+1) = (lo, hi)
#pragma unroll
      for (int c = 0; c < 2; c++) {
        bf16x8 ov;
#pragma unroll
        for (int j = 0; j < 4; j++) {
          ov[2 * j]     = (short)ngnn97_f2bf(lo[c * 4 + j]);
          ov[2 * j + 1] = (short)ngnn97_f2bf(hi[c * 4 + j]);
        }
        *(bf16x8*)(Abuf + row * 72 + sub * 16 + c * 8) = ov;
      }
    }
  }

  // ---- afrA frags from gathered agg (same-wave DS ordering: reads after own writes) ----
  bf16x8 afrA[2][2];
#pragma unroll
  for (int mm = 0; mm < 2; mm++)
#pragma unroll
    for (int kc = 0; kc < 2; kc++)
      afrA[mm][kc] = *(const bf16x8*)(Abuf + (mm * 16 + ncol) * 72 + quad * 8 + kc * 32);

  // ---- stage xh_old perm rows -> Abuf cols 0..63 (overwrite agg; in-order DS pipe) ----
#pragma unroll
  for (int i = 0; i < 8; i++) {
    int chunk = i * 64 + lane;                 // 512 = 32 rows x 16 ushort4
    int r2 = chunk >> 4, c4 = (chunk & 15) << 2;
    int node = pnode[r2];
    ushort4 qx = make_ushort4(0, 0, 0, 0);
    if (node < NN) qx = *(const ushort4*)(xh_old + (size_t)node * 64 + c4);
    *(ushort4*)(Abuf + r2 * 72 + c4) = qx;
  }

  bf16x8 afrX[2][2];
#pragma unroll
  for (int mm = 0; mm < 2; mm++)
#pragma unroll
    for (int kc = 0; kc < 2; kc++)
      afrX[mm][kc] = *(const bf16x8*)(Abuf + (mm * 16 + ncol) * 72 + quad * 8 + kc * 32);

  // ---- gate GEMM + GRU update; xn overwrites Abuf cols 0..63 ----
#pragma unroll
  for (int c = 0; c < 4; c++) {
    f32x4 aR[2], aZ[2], aN[2], aH[2];
#pragma unroll
    for (int mm = 0; mm < 2; mm++) {
      aR[mm] = (f32x4){0.f, 0.f, 0.f, 0.f}; aZ[mm] = aR[mm];
      aN[mm] = aR[mm]; aH[mm] = aR[mm];
    }
#pragma unroll
    for (int kc = 0; kc < 4; kc++) {
      const unsigned short* ub = Ubt + (size_t)(c * 16 + ncol) * 128 + quad * 8 + kc * 32;
      bf16x8 bR = *(const bf16x8*)(ub);
      bf16x8 bZ = *(const bf16x8*)(ub + 64 * 128);
      bf16x8 bX = (kc < 2) ? *(const bf16x8*)(ub + 128 * 128)
                           : *(const bf16x8*)(ub + 192 * 128);
#pragma unroll
      for (int mm = 0; mm < 2; mm++) {
        bf16x8 a = (kc < 2) ? afrA[mm][kc] : afrX[mm][kc - 2];
        aR[mm] = __builtin_amdgcn_mfma_f32_16x16x32_bf16(a, bR, aR[mm], 0, 0, 0);
        aZ[mm] = __builtin_amdgcn_mfma_f32_16x16x32_bf16(a, bZ, aZ[mm], 0, 0, 0);
        if (kc < 2) aN[mm] = __builtin_amdgcn_mfma_f32_16x16x32_bf16(a, bX, aN[mm], 0, 0, 0);
        else        aH[mm] = __builtin_amdgcn_mfma_f32_16x16x32_bf16(a, bX, aH[mm], 0, 0, 0);
      }
    }
    int j = c * 16 + ncol;
    float bRs = Ub[j], bZs = Ub[64 + j], bNs = Ub[128 + j], bHs = Ub[192 + j];
#pragma unroll
    for (int mm = 0; mm < 2; mm++)
#pragma unroll
      for (int r = 0; r < 4; r++) {
        int row = mm * 16 + quad * 4 + r;
        float R = aR[mm][r] + bRs, Z = aZ[mm][r] + bZs;
        float Nv = aN[mm][r] + bNs, H = aH[mm][r] + bHs;
        float rg = 1.f / (1.f + __expf(-R));
        float ug = 1.f / (1.f + __expf(-Z));
        float e2 = __expf(2.f * (Nv + rg * H));
        float nn2 = 1.f - 2.f / (e2 + 1.f);    // tanh via fast exp (saturates safely)
        float xo = ngnn97_bf2f(Abuf[row * 72 + j]);   // xh staged in cols 0..63
        Abuf[row * 72 + j] = ngnn97_f2bf((1.f - ug) * nn2 + ug * xo);
      }
  }

  if (do_transform) {
    // ---- A2-frags: xn from LDS, ze direct from bf16 ztab ----
    bf16x8 afrN[2][2], afrE[2][2];
#pragma unroll
    for (int mm = 0; mm < 2; mm++) {
      int node = pnode[mm * 16 + ncol];
      int zz = (node < NN) ? z[node] : 0;
#pragma unroll
      for (int kc = 0; kc < 2; kc++) {
        afrN[mm][kc] = *(const bf16x8*)(Abuf + (mm * 16 + ncol) * 72 + quad * 8 + kc * 32);
        afrE[mm][kc] = *(const bf16x8*)(ztabh + zz * 64 + quad * 8 + kc * 32);
      }
    }
    // ---- transform GEMM -> Abuf cols 0..63 ----
#pragma unroll
    for (int c2 = 0; c2 < 4; c2++) {
      f32x4 acc[2];
      acc[0] = (f32x4){0.f, 0.f, 0.f, 0.f}; acc[1] = acc[0];
#pragma unroll
      for (int kc = 0; kc < 4; kc++) {
        bf16x8 bV = *(const bf16x8*)(Vbt + (size_t)(c2 * 16 + ncol) * 128 + quad * 8 + kc * 32);
#pragma unroll
        for (int mm = 0; mm < 2; mm++) {
          bf16x8 a = (kc < 2) ? afrN[mm][kc] : afrE[mm][kc - 2];
          acc[mm] = __builtin_amdgcn_mfma_f32_16x16x32_bf16(a, bV, acc[mm], 0, 0, 0);
        }
      }
      int j = c2 * 16 + ncol;
      float bt = tfb[j];
#pragma unroll
      for (int mm = 0; mm < 2; mm++)
#pragma unroll
        for (int r = 0; r < 4; r++) {
          int row = mm * 16 + quad * 4 + r;
          Abuf[row * 72 + j] = ngnn97_f2bf(acc[mm][r] + bt);
        }
    }
  }

  // ---- store: Abuf cols 0..63 -> xh_new[perm rows] (128B segments per row) ----
#pragma unroll
  for (int i = 0; i < 8; i++) {
    int chunk = i * 64 + lane;
    int r2 = chunk >> 4, c4 = (chunk & 15) << 2;
    int node = pnode[r2];
    if (node < NN)
      *(ushort4*)(xh_new + (size_t)node * 64 + c4) = *(const ushort4*)(Abuf + r2 * 72 + c4);
  }
}

// ---------------- pooling: bucketed contiguous reduction ----------------
__global__ __launch_bounds__(256) void ngnn97_pool(const unsigned short* __restrict__ xh,
                                                   const int* __restrict__ nlist,
                                                   const int* __restrict__ gcur,
                                                   float* __restrict__ gpool) {
  __shared__ float part[4][64];
  int t = threadIdx.x;
  int lane = t & 63, wv = t >> 6;
  int g = blockIdx.x >> 4, c = blockIdx.x & 15;
  int cnt = gcur[g];
  if (cnt > GCAP) cnt = GCAP;
  int r0 = (c * cnt) >> 4, r1 = ((c + 1) * cnt) >> 4;
  const int* nl = nlist + g * GCAP;
  float a0 = 0.f, a1 = 0.f;
  int r = r0 + wv;
  for (; r + 4 < r1; r += 8) {
    int n0 = nl[r], n1 = nl[r + 4];
    a0 += ngnn97_bf2f(xh[(size_t)n0 * 64 + lane]);
    a1 += ngnn97_bf2f(xh[(size_t)n1 * 64 + lane]);
  }
  if (r < r1) a0 += ngnn97_bf2f(xh[(size_t)nl[r] * 64 + lane]);
  part[wv][lane] = a0 + a1;
  __syncthreads();
  if (t < 64)
    atomicAdd(&gpool[g * 64 + t], part[0][t] + part[1][t] + part[2][t] + part[3][t]);
}

// ---------------- MLP head (output: float32 [G,1]) ----------------
__global__ __launch_bounds__(256) void ngnn97_head(
    const float* __restrict__ gpool,
    const float* __restrict__ W1, const float* __restrict__ b1,
    const float* __restrict__ W2, const float* __restrict__ b2,
    const float* __restrict__ W3, const float* __restrict__ b3,
    float* __restrict__ out) {
  __shared__ float gp[4096];
  __shared__ float h1[2048];
  __shared__ float h2[1024];
  int t = threadIdx.x;
  for (int i = t; i < 4096; i += 256) gp[i] = gpool[i];
  __syncthreads();
  for (int i = t; i < 2048; i += 256) {
    int g = i >> 5, o = i & 31;
    float a = b1[o];
    for (int d = 0; d < 64; d++) a = fmaf(gp[g * 64 + d], W1[o * 64 + d], a);
    h1[i] = (a > 0.f) ? a : (__expf(a) - 1.f);
  }
  __syncthreads();
  for (int i = t; i < 1024; i += 256) {
    int g = i >> 4, o = i & 15;
    float a = b2[o];
    for (int d = 0; d < 32; d++) a = fmaf(h1[g * 32 + d], W2[o * 32 + d], a);
    h2[i] = (a > 0.f) ? a : (__expf(a) - 1.f);
  }
  __syncthreads();
  if (t < 64) {
    float a = b3[0];
    for (int d = 0; d < 16; d++) a = fmaf(h2[t * 16 + d], W3[d], a);
    out[t] = a;
  }
}

// ---------------- workspace layout (byte offsets) ----------------
#define OFF_XH0   ((size_t)0)                          // N*64 bf16 = 64,000,000
#define OFF_XH1   ((size_t)64000000)                   // N*64 bf16 = 64,000,000
#define OFF_CNT   ((size_t)128000000)                  // NP int
#define OFF_ROW   (OFF_CNT + (size_t)NP * 4)
#define OFF_CUR   (OFF_ROW + (size_t)NP * 4)
#define OFF_SRC   (OFF_CUR + (size_t)NP * 4)           // E+2 ints (+2: guard-free prefetch)
#define OFF_BSUM  (OFF_SRC + (size_t)(EE + 2) * 4)
#define OFF_BOFF  (OFF_BSUM + (size_t)2048)
#define OFF_U     (OFF_BOFF + (size_t)2048)            // Ubt bf16 5*256*128
#define OFF_UB    (OFF_U + (size_t)327680)             // Ub f32 5*256
#define OFF_V     (OFF_UB + (size_t)5120)              // Vbt bf16 4*64*128
#define OFF_GP    (OFF_V + (size_t)65536)              // gpool 64*64 f32
#define OFF_G8    (OFF_GP + (size_t)16384)             // N uint8 (padded)
#define OFF_ZTH   (OFF_G8 + (size_t)500736)            // ztabh bf16 5*100*64
#define OFF_GCUR  (OFF_ZTH + (size_t)64000)            // 64 ints (+pad)
#define OFF_NL    (OFF_GCUR + (size_t)1024)            // nlist 64*GCAP ints = 4 MB
#define OFF_PERM  (OFF_NL + (size_t)64 * GCAP * 4)     // segment-degree-sorted perm, NP ints
#define WS_NEED   (OFF_PERM + (size_t)NP * 4)          // ~= 146.2 MB (proven budget 203.8)

extern "C" void kernel_launch(void* const* d_in, const int* in_sizes, int n_in,
                              void* d_out, int out_size, void* d_ws, size_t ws_size,
                              hipStream_t stream) {
  float* out = (float*)d_out;   // reference output is float32 [G,1]
  if (ws_size < WS_NEED) {
    ngnn97_code<<<1, 64, 0, stream>>>(out, 7.0f);
    return;
  }

  const int* z    = (const int*)d_in[0];
  const int* ei   = (const int*)d_in[1];
  const int* n2s  = (const int*)d_in[2];
  const int* s2g  = (const int*)d_in[3];
  const float* ztab = (const float*)d_in[4];
  const float* tfW  = (const float*)d_in[5];
  const float* tfb  = (const float*)d_in[6];
  const float* ggc  = (const float*)d_in[7];
  const float* wih  = (const float*)d_in[8];
  const float* whh  = (const float*)d_in[9];
  const float* bih  = (const float*)d_in[10];
  const float* bhh  = (const float*)d_in[11];
  const float* W1   = (const float*)d_in[12];
  const float* b1   = (const float*)d_in[13];
  const float* W2   = (const float*)d_in[14];
  const float* b2   = (const float*)d_in[15];
  const float* W3   = (const float*)d_in[16];
  const float* b3   = (const float*)d_in[17];

  char* ws = (char*)d_ws;
  unsigned short* xh0    = (unsigned short*)(ws + OFF_XH0);
  unsigned short* xh1    = (unsigned short*)(ws + OFF_XH1);
  int*            counts = (int*)(ws + OFF_CNT);
  int*            rowp   = (int*)(ws + OFF_ROW);
  int*            curs   = (int*)(ws + OFF_CUR);
  int*            srcs   = (int*)(ws + OFF_SRC);
  int*            bsum   = (int*)(ws + OFF_BSUM);
  int*            boff   = (int*)(ws + OFF_BOFF);
  unsigned short* Ubt    = (unsigned short*)(ws + OFF_U);
  float*          Ub     = (float*)(ws + OFF_UB);
  unsigned short* Vbt    = (unsigned short*)(ws + OFF_V);
  float*          gpool  = (float*)(ws + OFF_GP);
  unsigned char*  g8     = (unsigned char*)(ws + OFF_G8);
  unsigned short* ztabh  = (unsigned short*)(ws + OFF_ZTH);
  int*            gcur   = (int*)(ws + OFF_GCUR);
  int*            nlist  = (int*)(ws + OFF_NL);
  int*            perm   = (int*)(ws + OFF_PERM);

  hipMemsetAsync(counts, 0, (size_t)NP * 4, stream);
  hipMemsetAsync(gpool, 0, 16384, stream);
  hipMemsetAsync(gcur, 0, 1024, stream);

  ngnn97_pre<<<899, 256, 0, stream>>>(ggc, wih, whh, bih, bhh, tfW, ztab, Ubt, Ub, Vbt, ztabh);
  ngnn97_g8<<<(NN + 255) / 256, 256, 0, stream>>>(n2s, s2g, g8);
  ngnn97_bucket<<<NBLK, 256, 0, stream>>>(g8, gcur, nlist);

  // CSR by dst
  const int* srcp = ei;
  const int* dstp = ei + EE;
  ngnn97_hist<<<(EE + 255) / 256, 256, 0, stream>>>(dstp, counts);
  ngnn97_red<<<NBLK, 256, 0, stream>>>(counts, bsum);
  ngnn97_scan1<<<1, 512, 0, stream>>>(bsum, boff);
  ngnn97_scan2<<<NBLK, 256, 0, stream>>>(counts, boff, rowp, curs);
  ngnn97_fill<<<(EE + 255) / 256, 256, 0, stream>>>(srcp, dstp, curs, srcs);
  // rowp[n]..rowp[n+1] bounds node n's incoming-edge list

  // segment-local degree-sorted permutation (one kernel)
  ngnn97_dsort<<<NBLK, 256, 0, stream>>>(rowp, perm);

  ngnn97_embed<<<(NN * 8 + 255) / 256, 256, 0, stream>>>(z, ztabh, xh0);

  unsigned short* xc = xh0;
  unsigned short* xn2 = xh1;
  for (int l = 0; l < 5; l++) {
    ngnn97_gru<<<(NN + 31) / 32, 64, 0, stream>>>(
        xc, xn2, rowp, srcs, perm,
        Ubt + (size_t)l * 32768, Ub + (size_t)l * 256,
        Vbt + (size_t)(l < 4 ? l : 0) * 8192, tfb + (size_t)(l < 4 ? l : 0) * 64,
        z, ztabh + (size_t)(l < 4 ? l + 1 : 0) * 6400, (l < 4) ? 1 : 0);
    unsigned short* tmp = xc; xc = xn2; xn2 = tmp;
  }
  // final state in xc

  ngnn97_pool<<<1024, 256, 0, stream>>>(xc, nlist, gcur, gpool);
  ngnn97_head<<<1, 256, 0, stream>>>(gpool, W1, b1, W2, b2, W3, b3, out);
}

// Round 10
// 1106.003 us; speedup vs baseline: 1.0305x; 1.0305x over previous
//
#include <hip/hip_runtime.h>
#include <hip/hip_bf16.h>

// ---------------- problem constants ----------------
#define NN 500000
#define EE 1250000
#define NP 501760          // padded node count
#define NBLK 489           // scan blocks of 1024
#define GCAP 16384         // nlist capacity per graph (expected 7812, 2.1x margin)

typedef __attribute__((ext_vector_type(8))) short bf16x8;
typedef __attribute__((ext_vector_type(4))) float f32x4;

__device__ __forceinline__ float ngnn97_bf2f(unsigned short u) {
  return __uint_as_float(((unsigned int)u) << 16);
}
__device__ __forceinline__ unsigned short ngnn97_f2bf(float f) {
  union { __hip_bfloat16 b; unsigned short u; } cv;
  cv.b = __float2bfloat16(f);
  return cv.u;
}
// accumulate 4 dwords (8 bf16) into lo/hi f32 accumulators, dword-wise
__device__ __forceinline__ void ngnn97_acc8(uint4 u, float* lo, float* hi) {
  lo[0] += __uint_as_float(u.x << 16); hi[0] += __uint_as_float(u.x & 0xFFFF0000u);
  lo[1] += __uint_as_float(u.y << 16); hi[1] += __uint_as_float(u.y & 0xFFFF0000u);
  lo[2] += __uint_as_float(u.z << 16); hi[2] += __uint_as_float(u.z & 0xFFFF0000u);
  lo[3] += __uint_as_float(u.w << 16); hi[3] += __uint_as_float(u.w & 0xFFFF0000u);
}

// ---------------- diagnostic code writer (guard path only) ----------------
__global__ void ngnn97_code(float* __restrict__ out, float v) {
  if (threadIdx.x < 64) out[threadIdx.x] = v;
}

// ---------------- precompute folded weights (bf16, MFMA-B layout) + bf16 ztab ----------------
__global__ __launch_bounds__(256) void ngnn97_pre(
    const float* __restrict__ ggc, const float* __restrict__ wih,
    const float* __restrict__ whh, const float* __restrict__ bih,
    const float* __restrict__ bhh, const float* __restrict__ tfW,
    const float* __restrict__ ztab,
    unsigned short* __restrict__ Ubt, float* __restrict__ Ub,
    unsigned short* __restrict__ Vbt, unsigned short* __restrict__ ztabh) {
  int idx = blockIdx.x * 256 + threadIdx.x;
  if (idx < 163840) {                      // Ubt: 5*256*128
    int l = idx >> 15, r = idx & 32767;
    int n = r >> 7, k = r & 127;
    float v = 0.f;
    if (k < 64) {
      if (n < 192) {
        const float* gp = ggc + l * 4096 + k * 64;
        const float* wp = wih + l * 12288 + n * 64;
        float acc = 0.f;
#pragma unroll
        for (int t2 = 0; t2 < 64; t2++) acc = fmaf(gp[t2], wp[t2], acc);
        v = acc;
      }
    } else {
      int k2 = k - 64;
      if (n < 128) v = whh[l * 12288 + n * 64 + k2];
      else if (n >= 192) v = whh[l * 12288 + (n - 64) * 64 + k2];
    }
    Ubt[idx] = ngnn97_f2bf(v);
  } else if (idx < 196608) {               // Vbt: 4*64*128 (= tfW flat)
    int i2 = idx - 163840;
    Vbt[i2] = ngnn97_f2bf(tfW[i2]);
  } else if (idx < 197888) {               // Ub: 5*256
    int i2 = idx - 196608;
    int l = i2 >> 8, j = i2 & 255;
    float v;
    if (j < 128)      v = bih[l * 192 + j] + bhh[l * 192 + j];
    else if (j < 192) v = bih[l * 192 + j];
    else              v = bhh[l * 192 + j - 64];
    Ub[i2] = v;
  } else if (idx < 229888) {               // ztabh: 5*100*64 bf16
    int i2 = idx - 197888;
    ztabh[i2] = ngnn97_f2bf(ztab[i2]);
  }
}

// ---------------- CSR build ----------------
__global__ __launch_bounds__(256) void ngnn97_hist(const int* __restrict__ dst, int* __restrict__ counts) {
  int e = blockIdx.x * 256 + threadIdx.x;
  if (e < EE) atomicAdd(&counts[dst[e]], 1);
}

__global__ __launch_bounds__(256) void ngnn97_red(const int* __restrict__ counts, int* __restrict__ bsum) {
  __shared__ int s[256];
  int t = threadIdx.x, base = blockIdx.x * 1024;
  int v = 0;
#pragma unroll
  for (int i = 0; i < 4; i++) v += counts[base + t + i * 256];
  s[t] = v; __syncthreads();
  for (int o = 128; o > 0; o >>= 1) { if (t < o) s[t] += s[t + o]; __syncthreads(); }
  if (t == 0) bsum[blockIdx.x] = s[0];
}

__global__ __launch_bounds__(512) void ngnn97_scan1(const int* __restrict__ bsum, int* __restrict__ boff) {
  __shared__ int s[512];
  int t = threadIdx.x;
  int v = (t < NBLK) ? bsum[t] : 0;
  s[t] = v; __syncthreads();
  for (int o = 1; o < 512; o <<= 1) {
    int a = (t >= o) ? s[t - o] : 0;
    __syncthreads(); s[t] += a; __syncthreads();
  }
  if (t < NBLK) boff[t] = s[t] - v;   // exclusive
}

__global__ __launch_bounds__(256) void ngnn97_scan2(const int* __restrict__ counts, const int* __restrict__ boff,
                                                    int* __restrict__ row_ptr, int* __restrict__ cursor) {
  __shared__ int s[256];
  int t = threadIdx.x, base = blockIdx.x * 1024;
  int4 c = *(const int4*)(counts + base + t * 4);
  int tsum = c.x + c.y + c.z + c.w;
  s[t] = tsum; __syncthreads();
  for (int o = 1; o < 256; o <<= 1) {
    int a = (t >= o) ? s[t - o] : 0;
    __syncthreads(); s[t] += a; __syncthreads();
  }
  int off = boff[blockIdx.x] + s[t] - tsum;
  int4 r;
  r.x = off; r.y = off + c.x; r.z = off + c.x + c.y; r.w = off + c.x + c.y + c.z;
  *(int4*)(row_ptr + base + t * 4) = r;
  *(int4*)(cursor + base + t * 4) = r;
}

__global__ __launch_bounds__(256) void ngnn97_fill(const int* __restrict__ src, const int* __restrict__ dst,
                                                   int* __restrict__ cursor, int* __restrict__ srcs) {
  int e = blockIdx.x * 256 + threadIdx.x;
  if (e < EE) {
    int pos = atomicAdd(&cursor[dst[e]], 1);
    srcs[pos] = src[e];
  }
}

// ---------------- node -> graph id precompute (uint8) ----------------
__global__ __launch_bounds__(256) void ngnn97_g8(const int* __restrict__ n2s, const int* __restrict__ s2g,
                                                 unsigned char* __restrict__ g8) {
  int idx = blockIdx.x * 256 + threadIdx.x;
  if (idx < NN) g8[idx] = (unsigned char)s2g[n2s[idx]];
}

// ---------------- bucket nodes by graph: LDS hist + two-pass fill ----------------
__global__ __launch_bounds__(256) void ngnn97_bucket(const unsigned char* __restrict__ g8,
                                                     int* __restrict__ gcur, int* __restrict__ nlist) {
  __shared__ int hcnt[64];
  __shared__ int hbase[64];
  int t = threadIdx.x;
  int base = blockIdx.x * 1024;
  if (t < 64) hcnt[t] = 0;
  __syncthreads();
#pragma unroll
  for (int i = 0; i < 4; i++) {
    int node = base + i * 256 + t;
    if (node < NN) atomicAdd(&hcnt[g8[node]], 1);
  }
  __syncthreads();
  if (t < 64) {
    int c = hcnt[t];
    hbase[t] = (c > 0) ? atomicAdd(&gcur[t], c) : 0;
    hcnt[t] = 0;
  }
  __syncthreads();
#pragma unroll
  for (int i = 0; i < 4; i++) {
    int node = base + i * 256 + t;
    if (node < NN) {
      int g = g8[node];
      int loc = atomicAdd(&hcnt[g], 1);
      int pos = hbase[g] + loc;
      if (pos < GCAP) nlist[g * GCAP + pos] = node;
    }
  }
}

// ---------------- degree-sort: counting sort of nodes by CSR in-degree ----------------
// Uniform-degree waves: gather serial time = avg (not max) chain, no masked-VALU waste.
__global__ __launch_bounds__(256) void ngnn97_dhist(const int* __restrict__ rowp, int* __restrict__ dbins) {
  __shared__ int h[64];
  int t = threadIdx.x, base = blockIdx.x * 1024;
  if (t < 64) h[t] = 0;
  __syncthreads();
#pragma unroll
  for (int i = 0; i < 4; i++) {
    int node = base + i * 256 + t;
    if (node < NN) {
      int d = rowp[node + 1] - rowp[node];
      if (d > 63) d = 63;
      atomicAdd(&h[d], 1);
    }
  }
  __syncthreads();
  if (t < 64 && h[t]) atomicAdd(&dbins[t], h[t]);
}

__global__ __launch_bounds__(64) void ngnn97_dscan(const int* __restrict__ dbins, int* __restrict__ dcur) {
  __shared__ int s[64];
  int t = threadIdx.x;
  int v = dbins[t];
  s[t] = v; __syncthreads();
  for (int o = 1; o < 64; o <<= 1) {
    int a = (t >= o) ? s[t - o] : 0;
    __syncthreads(); s[t] += a; __syncthreads();
  }
  dcur[t] = s[t] - v;   // exclusive prefix
}

__global__ __launch_bounds__(256) void ngnn97_dfill(const int* __restrict__ rowp, int* __restrict__ dcur,
                                                    int* __restrict__ perm) {
  __shared__ int hcnt[64];
  __shared__ int hbase[64];
  int t = threadIdx.x, base = blockIdx.x * 1024;
  if (t < 64) hcnt[t] = 0;
  __syncthreads();
#pragma unroll
  for (int i = 0; i < 4; i++) {
    int node = base + i * 256 + t;
    if (node < NN) {
      int d = rowp[node + 1] - rowp[node];
      if (d > 63) d = 63;
      atomicAdd(&hcnt[d], 1);
    }
  }
  __syncthreads();
  if (t < 64) {
    int c = hcnt[t];
    hbase[t] = (c > 0) ? atomicAdd(&dcur[t], c) : 0;
    hcnt[t] = 0;
  }
  __syncthreads();
#pragma unroll
  for (int i = 0; i < 4; i++) {
    int node = base + i * 256 + t;
    if (node < NN) {
      int d = rowp[node + 1] - rowp[node];
      if (d > 63) d = 63;
      int loc = atomicAdd(&hcnt[d], 1);
      perm[hbase[d] + loc] = node;
    }
  }
}

// ---------------- layer-0 embedding: bf16x8 row copies from ztabh ----------------
__global__ __launch_bounds__(256) void ngnn97_embed(const int* __restrict__ z,
                                                    const unsigned short* __restrict__ ztabh,
                                                    unsigned short* __restrict__ xh) {
  int idx = blockIdx.x * 256 + threadIdx.x;
  int node = idx >> 3, sub = idx & 7;
  if (node < NN) {
    int zz = z[node];
    *(bf16x8*)(xh + (size_t)node * 64 + sub * 8) =
        *(const bf16x8*)(ztabh + zz * 64 + sub * 8);
  }
}

// ---------------- FUSED gather + GRU via MFMA (+ optional transform) ----------------
// r7-proven structure (1066 us): 1-wave blocks (64 thr, 32 permuted nodes), zero
// barriers, 4.7 KB LDS, no launch-bounds squeeze (natural ~60 VGPR -> 4 waves/SIMD;
// wg-slot limit also caps at 4 -> both constraints agree, occupancy lever closed).
// NEW vs r7 (single change): traverse perm in DESCENDING degree order
// (pnode = perm[NN-1-idx]) -> hub (longest) blocks launch FIRST and drain under
// the sea of short low-degree blocks (longest-job-first; r7 ran hubs last = tail).
// Bijective flip, per-node accumulation order untouched -> bit-identical results.
__global__ __launch_bounds__(64, 4) void ngnn97_gru(
    const unsigned short* __restrict__ xh_old, unsigned short* __restrict__ xh_new,
    const int* __restrict__ rowp, const int* __restrict__ srcs,
    const int* __restrict__ perm,
    const unsigned short* __restrict__ Ubt, const float* __restrict__ Ub,
    const unsigned short* __restrict__ Vbt, const float* __restrict__ tfb,
    const int* __restrict__ z, const unsigned short* __restrict__ ztabh,
    int do_transform) {
  __shared__ unsigned short Abuf[32 * 72];     // 4.6 KB: agg -> xh -> xn scratch
  __shared__ int pnode[32];
  const int lane = threadIdx.x;                // 1 wave
  const int ncol = lane & 15, quad = lane >> 4;
  const int nbase = blockIdx.x * 32;

  if (lane < 32) {
    int idx = nbase + lane;
    pnode[lane] = (idx < NN) ? perm[NN - 1 - idx] : NN;  // descending degree; NN = inactive
  }
  // same-wave DS ordering: all later reads see these writes

  // ---- gather: 2 sub-batches x 16 rows, 4 lanes (sub) per row -> Abuf cols 0..63 ----
  {
    int grp = lane >> 2, sub = lane & 3;       // grp 0..15; sub owns elems [sub*16,+16)
#pragma unroll
    for (int sb = 0; sb < 2; sb++) {
      int row = sb * 16 + grp;
      int node = pnode[row];
      float lo[8], hi[8];
#pragma unroll
      for (int i = 0; i < 8; i++) { lo[i] = 0.f; hi[i] = 0.f; }
      if (node < NN) {
        int b = rowp[node], e = rowp[node + 1];
        int p = b;
        for (; p + 2 <= e; p += 2) {
          int s0 = srcs[p], s1 = srcs[p + 1];
          const unsigned short* r0 = xh_old + (size_t)s0 * 64 + sub * 16;
          const unsigned short* r1 = xh_old + (size_t)s1 * 64 + sub * 16;
          uint4 u0 = *(const uint4*)(r0);
          uint4 u1 = *(const uint4*)(r0 + 8);
          uint4 u2 = *(const uint4*)(r1);
          uint4 u3 = *(const uint4*)(r1 + 8);
          ngnn97_acc8(u0, lo, hi); ngnn97_acc8(u1, lo + 4, hi + 4);
          ngnn97_acc8(u2, lo, hi); ngnn97_acc8(u3, lo + 4, hi + 4);
        }
        if (p < e) {
          const unsigned short* r0 = xh_old + (size_t)srcs[p] * 64 + sub * 16;
          uint4 u0 = *(const uint4*)(r0);
          uint4 u1 = *(const uint4*)(r0 + 8);
          ngnn97_acc8(u0, lo, hi);
          ngnn97_acc8(u1, lo + 4, hi + 4);
        }
      }
      // pack: dword j of chunk c -> elements (c*8+2j, c*8+2j+1) = (lo, hi)
#pragma unroll
      for (int c = 0; c < 2; c++) {
        bf16x8 ov;
#pragma unroll
        for (int j = 0; j < 4; j++) {
          ov[2 * j]     = (short)ngnn97_f2bf(lo[c * 4 + j]);
          ov[2 * j + 1] = (short)ngnn97_f2bf(hi[c * 4 + j]);
        }
        *(bf16x8*)(Abuf + row * 72 + sub * 16 + c * 8) = ov;
      }
    }
  }

  // ---- afrA frags from gathered agg (same-wave DS ordering: reads after own writes) ----
  bf16x8 afrA[2][2];
#pragma unroll
  for (int mm = 0; mm < 2; mm++)
#pragma unroll
    for (int kc = 0; kc < 2; kc++)
      afrA[mm][kc] = *(const bf16x8*)(Abuf + (mm * 16 + ncol) * 72 + quad * 8 + kc * 32);

  // ---- stage xh_old perm rows -> Abuf cols 0..63 (overwrite agg; in-order DS pipe) ----
#pragma unroll
  for (int i = 0; i < 8; i++) {
    int chunk = i * 64 + lane;                 // 512 = 32 rows x 16 ushort4
    int r2 = chunk >> 4, c4 = (chunk & 15) << 2;
    int node = pnode[r2];
    ushort4 qx = make_ushort4(0, 0, 0, 0);
    if (node < NN) qx = *(const ushort4*)(xh_old + (size_t)node * 64 + c4);
    *(ushort4*)(Abuf + r2 * 72 + c4) = qx;
  }

  bf16x8 afrX[2][2];
#pragma unroll
  for (int mm = 0; mm < 2; mm++)
#pragma unroll
    for (int kc = 0; kc < 2; kc++)
      afrX[mm][kc] = *(const bf16x8*)(Abuf + (mm * 16 + ncol) * 72 + quad * 8 + kc * 32);

  // ---- gate GEMM + GRU update; xn overwrites Abuf cols 0..63 ----
#pragma unroll
  for (int c = 0; c < 4; c++) {
    f32x4 aR[2], aZ[2], aN[2], aH[2];
#pragma unroll
    for (int mm = 0; mm < 2; mm++) {
      aR[mm] = (f32x4){0.f, 0.f, 0.f, 0.f}; aZ[mm] = aR[mm];
      aN[mm] = aR[mm]; aH[mm] = aR[mm];
    }
#pragma unroll
    for (int kc = 0; kc < 4; kc++) {
      const unsigned short* ub = Ubt + (size_t)(c * 16 + ncol) * 128 + quad * 8 + kc * 32;
      bf16x8 bR = *(const bf16x8*)(ub);
      bf16x8 bZ = *(const bf16x8*)(ub + 64 * 128);
      bf16x8 bX = (kc < 2) ? *(const bf16x8*)(ub + 128 * 128)
                           : *(const bf16x8*)(ub + 192 * 128);
#pragma unroll
      for (int mm = 0; mm < 2; mm++) {
        bf16x8 a = (kc < 2) ? afrA[mm][kc] : afrX[mm][kc - 2];
        aR[mm] = __builtin_amdgcn_mfma_f32_16x16x32_bf16(a, bR, aR[mm], 0, 0, 0);
        aZ[mm] = __builtin_amdgcn_mfma_f32_16x16x32_bf16(a, bZ, aZ[mm], 0, 0, 0);
        if (kc < 2) aN[mm] = __builtin_amdgcn_mfma_f32_16x16x32_bf16(a, bX, aN[mm], 0, 0, 0);
        else        aH[mm] = __builtin_amdgcn_mfma_f32_16x16x32_bf16(a, bX, aH[mm], 0, 0, 0);
      }
    }
    int j = c * 16 + ncol;
    float bRs = Ub[j], bZs = Ub[64 + j], bNs = Ub[128 + j], bHs = Ub[192 + j];
#pragma unroll
    for (int mm = 0; mm < 2; mm++)
#pragma unroll
      for (int r = 0; r < 4; r++) {
        int row = mm * 16 + quad * 4 + r;
        float R = aR[mm][r] + bRs, Z = aZ[mm][r] + bZs;
        float Nv = aN[mm][r] + bNs, H = aH[mm][r] + bHs;
        float rg = 1.f / (1.f + __expf(-R));
        float ug = 1.f / (1.f + __expf(-Z));
        float e2 = __expf(2.f * (Nv + rg * H));
        float nn2 = 1.f - 2.f / (e2 + 1.f);    // tanh via fast exp (saturates safely)
        float xo = ngnn97_bf2f(Abuf[row * 72 + j]);   // xh staged in cols 0..63
        Abuf[row * 72 + j] = ngnn97_f2bf((1.f - ug) * nn2 + ug * xo);
      }
  }

  if (do_transform) {
    // ---- A2-frags: xn from LDS, ze direct from bf16 ztab ----
    bf16x8 afrN[2][2], afrE[2][2];
#pragma unroll
    for (int mm = 0; mm < 2; mm++) {
      int node = pnode[mm * 16 + ncol];
      int zz = (node < NN) ? z[node] : 0;
#pragma unroll
      for (int kc = 0; kc < 2; kc++) {
        afrN[mm][kc] = *(const bf16x8*)(Abuf + (mm * 16 + ncol) * 72 + quad * 8 + kc * 32);
        afrE[mm][kc] = *(const bf16x8*)(ztabh + zz * 64 + quad * 8 + kc * 32);
      }
    }
    // ---- transform GEMM -> Abuf cols 0..63 ----
#pragma unroll
    for (int c2 = 0; c2 < 4; c2++) {
      f32x4 acc[2];
      acc[0] = (f32x4){0.f, 0.f, 0.f, 0.f}; acc[1] = acc[0];
#pragma unroll
      for (int kc = 0; kc < 4; kc++) {
        bf16x8 bV = *(const bf16x8*)(Vbt + (size_t)(c2 * 16 + ncol) * 128 + quad * 8 + kc * 32);
#pragma unroll
        for (int mm = 0; mm < 2; mm++) {
          bf16x8 a = (kc < 2) ? afrN[mm][kc] : afrE[mm][kc - 2];
          acc[mm] = __builtin_amdgcn_mfma_f32_16x16x32_bf16(a, bV, acc[mm], 0, 0, 0);
        }
      }
      int j = c2 * 16 + ncol;
      float bt = tfb[j];
#pragma unroll
      for (int mm = 0; mm < 2; mm++)
#pragma unroll
        for (int r = 0; r < 4; r++) {
          int row = mm * 16 + quad * 4 + r;
          Abuf[row * 72 + j] = ngnn97_f2bf(acc[mm][r] + bt);
        }
    }
  }

  // ---- store: Abuf cols 0..63 -> xh_new[perm rows] (128B segments per row) ----
#pragma unroll
  for (int i = 0; i < 8; i++) {
    int chunk = i * 64 + lane;
    int r2 = chunk >> 4, c4 = (chunk & 15) << 2;
    int node = pnode[r2];
    if (node < NN)
      *(ushort4*)(xh_new + (size_t)node * 64 + c4) = *(const ushort4*)(Abuf + r2 * 72 + c4);
  }
}

// ---------------- pooling: bucketed contiguous reduction ----------------
__global__ __launch_bounds__(256) void ngnn97_pool(const unsigned short* __restrict__ xh,
                                                   const int* __restrict__ nlist,
                                                   const int* __restrict__ gcur,
                                                   float* __restrict__ gpool) {
  __shared__ float part[4][64];
  int t = threadIdx.x;
  int lane = t & 63, wv = t >> 6;
  int g = blockIdx.x >> 4, c = blockIdx.x & 15;
  int cnt = gcur[g];
  if (cnt > GCAP) cnt = GCAP;
  int r0 = (c * cnt) >> 4, r1 = ((c + 1) * cnt) >> 4;
  const int* nl = nlist + g * GCAP;
  float a0 = 0.f, a1 = 0.f;
  int r = r0 + wv;
  for (; r + 4 < r1; r += 8) {
    int n0 = nl[r], n1 = nl[r + 4];
    a0 += ngnn97_bf2f(xh[(size_t)n0 * 64 + lane]);
    a1 += ngnn97_bf2f(xh[(size_t)n1 * 64 + lane]);
  }
  if (r < r1) a0 += ngnn97_bf2f(xh[(size_t)nl[r] * 64 + lane]);
  part[wv][lane] = a0 + a1;
  __syncthreads();
  if (t < 64)
    atomicAdd(&gpool[g * 64 + t], part[0][t] + part[1][t] + part[2][t] + part[3][t]);
}

// ---------------- MLP head (output: float32 [G,1]) ----------------
__global__ __launch_bounds__(256) void ngnn97_head(
    const float* __restrict__ gpool,
    const float* __restrict__ W1, const float* __restrict__ b1,
    const float* __restrict__ W2, const float* __restrict__ b2,
    const float* __restrict__ W3, const float* __restrict__ b3,
    float* __restrict__ out) {
  __shared__ float gp[4096];
  __shared__ float h1[2048];
  __shared__ float h2[1024];
  int t = threadIdx.x;
  for (int i = t; i < 4096; i += 256) gp[i] = gpool[i];
  __syncthreads();
  for (int i = t; i < 2048; i += 256) {
    int g = i >> 5, o = i & 31;
    float a = b1[o];
    for (int d = 0; d < 64; d++) a = fmaf(gp[g * 64 + d], W1[o * 64 + d], a);
    h1[i] = (a > 0.f) ? a : (__expf(a) - 1.f);
  }
  __syncthreads();
  for (int i = t; i < 1024; i += 256) {
    int g = i >> 4, o = i & 15;
    float a = b2[o];
    for (int d = 0; d < 32; d++) a = fmaf(h1[g * 32 + d], W2[o * 32 + d], a);
    h2[i] = (a > 0.f) ? a : (__expf(a) - 1.f);
  }
  __syncthreads();
  if (t < 64) {
    float a = b3[0];
    for (int d = 0; d < 16; d++) a = fmaf(h2[t * 16 + d], W3[d], a);
    out[t] = a;
  }
}

// ---------------- workspace layout (byte offsets) ----------------
#define OFF_XH0   ((size_t)0)                          // N*64 bf16 = 64,000,000
#define OFF_XH1   ((size_t)64000000)                   // N*64 bf16 = 64,000,000
#define OFF_CNT   ((size_t)128000000)                  // NP int
#define OFF_ROW   (OFF_CNT + (size_t)NP * 4)
#define OFF_CUR   (OFF_ROW + (size_t)NP * 4)
#define OFF_SRC   (OFF_CUR + (size_t)NP * 4)           // E int
#define OFF_BSUM  (OFF_SRC + (size_t)EE * 4)
#define OFF_BOFF  (OFF_BSUM + (size_t)2048)
#define OFF_U     (OFF_BOFF + (size_t)2048)            // Ubt bf16 5*256*128
#define OFF_UB    (OFF_U + (size_t)327680)             // Ub f32 5*256
#define OFF_V     (OFF_UB + (size_t)5120)              // Vbt bf16 4*64*128
#define OFF_GP    (OFF_V + (size_t)65536)              // gpool 64*64 f32
#define OFF_G8    (OFF_GP + (size_t)16384)             // N uint8 (padded)
#define OFF_ZTH   (OFF_G8 + (size_t)500736)            // ztabh bf16 5*100*64
#define OFF_GCUR  (OFF_ZTH + (size_t)64000)            // 64 ints (+pad)
#define OFF_NL    (OFF_GCUR + (size_t)1024)            // nlist 64*GCAP ints = 4 MB
#define OFF_PERM  (OFF_NL + (size_t)64 * GCAP * 4)     // degree-sorted node perm, NP ints
#define OFF_DB    (OFF_PERM + (size_t)NP * 4)          // degree bins, 64 ints
#define OFF_DC    (OFF_DB + (size_t)256)               // degree cursors, 64 ints
#define WS_NEED   (OFF_DC + (size_t)256)               // ~= 146.2 MB (proven budget 203.8)

extern "C" void kernel_launch(void* const* d_in, const int* in_sizes, int n_in,
                              void* d_out, int out_size, void* d_ws, size_t ws_size,
                              hipStream_t stream) {
  float* out = (float*)d_out;   // reference output is float32 [G,1]
  if (ws_size < WS_NEED) {
    ngnn97_code<<<1, 64, 0, stream>>>(out, 7.0f);
    return;
  }

  const int* z    = (const int*)d_in[0];
  const int* ei   = (const int*)d_in[1];
  const int* n2s  = (const int*)d_in[2];
  const int* s2g  = (const int*)d_in[3];
  const float* ztab = (const float*)d_in[4];
  const float* tfW  = (const float*)d_in[5];
  const float* tfb  = (const float*)d_in[6];
  const float* ggc  = (const float*)d_in[7];
  const float* wih  = (const float*)d_in[8];
  const float* whh  = (const float*)d_in[9];
  const float* bih  = (const float*)d_in[10];
  const float* bhh  = (const float*)d_in[11];
  const float* W1   = (const float*)d_in[12];
  const float* b1   = (const float*)d_in[13];
  const float* W2   = (const float*)d_in[14];
  const float* b2   = (const float*)d_in[15];
  const float* W3   = (const float*)d_in[16];
  const float* b3   = (const float*)d_in[17];

  char* ws = (char*)d_ws;
  unsigned short* xh0    = (unsigned short*)(ws + OFF_XH0);
  unsigned short* xh1    = (unsigned short*)(ws + OFF_XH1);
  int*            counts = (int*)(ws + OFF_CNT);
  int*            rowp   = (int*)(ws + OFF_ROW);
  int*            curs   = (int*)(ws + OFF_CUR);
  int*            srcs   = (int*)(ws + OFF_SRC);
  int*            bsum   = (int*)(ws + OFF_BSUM);
  int*            boff   = (int*)(ws + OFF_BOFF);
  unsigned short* Ubt    = (unsigned short*)(ws + OFF_U);
  float*          Ub     = (float*)(ws + OFF_UB);
  unsigned short* Vbt    = (unsigned short*)(ws + OFF_V);
  float*          gpool  = (float*)(ws + OFF_GP);
  unsigned char*  g8     = (unsigned char*)(ws + OFF_G8);
  unsigned short* ztabh  = (unsigned short*)(ws + OFF_ZTH);
  int*            gcur   = (int*)(ws + OFF_GCUR);
  int*            nlist  = (int*)(ws + OFF_NL);
  int*            perm   = (int*)(ws + OFF_PERM);
  int*            dbins  = (int*)(ws + OFF_DB);
  int*            dcur   = (int*)(ws + OFF_DC);

  hipMemsetAsync(counts, 0, (size_t)NP * 4, stream);
  hipMemsetAsync(gpool, 0, 16384, stream);
  hipMemsetAsync(gcur, 0, 1024, stream);
  hipMemsetAsync(dbins, 0, 256, stream);

  ngnn97_pre<<<899, 256, 0, stream>>>(ggc, wih, whh, bih, bhh, tfW, ztab, Ubt, Ub, Vbt, ztabh);
  ngnn97_g8<<<(NN + 255) / 256, 256, 0, stream>>>(n2s, s2g, g8);
  ngnn97_bucket<<<NBLK, 256, 0, stream>>>(g8, gcur, nlist);

  // CSR by dst
  const int* srcp = ei;
  const int* dstp = ei + EE;
  ngnn97_hist<<<(EE + 255) / 256, 256, 0, stream>>>(dstp, counts);
  ngnn97_red<<<NBLK, 256, 0, stream>>>(counts, bsum);
  ngnn97_scan1<<<1, 512, 0, stream>>>(bsum, boff);
  ngnn97_scan2<<<NBLK, 256, 0, stream>>>(counts, boff, rowp, curs);
  ngnn97_fill<<<(EE + 255) / 256, 256, 0, stream>>>(srcp, dstp, curs, srcs);
  // rowp[n]..rowp[n+1] bounds node n's incoming-edge list

  // degree-sorted permutation (counting sort, 64 bins)
  ngnn97_dhist<<<NBLK, 256, 0, stream>>>(rowp, dbins);
  ngnn97_dscan<<<1, 64, 0, stream>>>(dbins, dcur);
  ngnn97_dfill<<<NBLK, 256, 0, stream>>>(rowp, dcur, perm);

  ngnn97_embed<<<(NN * 8 + 255) / 256, 256, 0, stream>>>(z, ztabh, xh0);

  unsigned short* xc = xh0;
  unsigned short* xn2 = xh1;
  for (int l = 0; l < 5; l++) {
    ngnn97_gru<<<(NN + 31) / 32, 64, 0, stream>>>(
        xc, xn2, rowp, srcs, perm,
        Ubt + (size_t)l * 32768, Ub + (size_t)l * 256,
        Vbt + (size_t)(l < 4 ? l : 0) * 8192, tfb + (size_t)(l < 4 ? l : 0) * 64,
        z, ztabh + (size_t)(l < 4 ? l + 1 : 0) * 6400, (l < 4) ? 1 : 0);
    unsigned short* tmp = xc; xc = xn2; xn2 = tmp;
  }
  // final state in xc

  ngnn97_pool<<<1024, 256, 0, stream>>>(xc, nlist, gcur, gpool);
  ngnn97_head<<<1, 256, 0, stream>>>(gpool, W1, b1, W2, b2, W3, b3, out);
}

// Round 11
// 1062.689 us; speedup vs baseline: 1.0725x; 1.0408x over previous
//
#include <hip/hip_runtime.h>
#include <hip/hip_bf16.h>

// ---------------- problem constants ----------------
#define NN 500000
#define EE 1250000
#define NP 501760          // padded node count
#define NBLK 489           // scan blocks of 1024
#define GCAP 16384         // nlist capacity per graph (expected 7812, 2.1x margin)

typedef __attribute__((ext_vector_type(8))) short bf16x8;
typedef __attribute__((ext_vector_type(4))) float f32x4;

__device__ __forceinline__ float ngnn97_bf2f(unsigned short u) {
  return __uint_as_float(((unsigned int)u) << 16);
}
__device__ __forceinline__ unsigned short ngnn97_f2bf(float f) {
  union { __hip_bfloat16 b; unsigned short u; } cv;
  cv.b = __float2bfloat16(f);
  return cv.u;
}
// accumulate 4 dwords (8 bf16) into lo/hi f32 accumulators, dword-wise
__device__ __forceinline__ void ngnn97_acc8(uint4 u, float* lo, float* hi) {
  lo[0] += __uint_as_float(u.x << 16); hi[0] += __uint_as_float(u.x & 0xFFFF0000u);
  lo[1] += __uint_as_float(u.y << 16); hi[1] += __uint_as_float(u.y & 0xFFFF0000u);
  lo[2] += __uint_as_float(u.z << 16); hi[2] += __uint_as_float(u.z & 0xFFFF0000u);
  lo[3] += __uint_as_float(u.w << 16); hi[3] += __uint_as_float(u.w & 0xFFFF0000u);
}

// ---------------- diagnostic code writer (guard path only) ----------------
__global__ void ngnn97_code(float* __restrict__ out, float v) {
  if (threadIdx.x < 64) out[threadIdx.x] = v;
}

// ---------------- precompute folded weights (bf16, MFMA-B layout) + bf16 ztab ----------------
__global__ __launch_bounds__(256) void ngnn97_pre(
    const float* __restrict__ ggc, const float* __restrict__ wih,
    const float* __restrict__ whh, const float* __restrict__ bih,
    const float* __restrict__ bhh, const float* __restrict__ tfW,
    const float* __restrict__ ztab,
    unsigned short* __restrict__ Ubt, float* __restrict__ Ub,
    unsigned short* __restrict__ Vbt, unsigned short* __restrict__ ztabh) {
  int idx = blockIdx.x * 256 + threadIdx.x;
  if (idx < 163840) {                      // Ubt: 5*256*128
    int l = idx >> 15, r = idx & 32767;
    int n = r >> 7, k = r & 127;
    float v = 0.f;
    if (k < 64) {
      if (n < 192) {
        const float* gp = ggc + l * 4096 + k * 64;
        const float* wp = wih + l * 12288 + n * 64;
        float acc = 0.f;
#pragma unroll
        for (int t2 = 0; t2 < 64; t2++) acc = fmaf(gp[t2], wp[t2], acc);
        v = acc;
      }
    } else {
      int k2 = k - 64;
      if (n < 128) v = whh[l * 12288 + n * 64 + k2];
      else if (n >= 192) v = whh[l * 12288 + (n - 64) * 64 + k2];
    }
    Ubt[idx] = ngnn97_f2bf(v);
  } else if (idx < 196608) {               // Vbt: 4*64*128 (= tfW flat)
    int i2 = idx - 163840;
    Vbt[i2] = ngnn97_f2bf(tfW[i2]);
  } else if (idx < 197888) {               // Ub: 5*256
    int i2 = idx - 196608;
    int l = i2 >> 8, j = i2 & 255;
    float v;
    if (j < 128)      v = bih[l * 192 + j] + bhh[l * 192 + j];
    else if (j < 192) v = bih[l * 192 + j];
    else              v = bhh[l * 192 + j - 64];
    Ub[i2] = v;
  } else if (idx < 229888) {               // ztabh: 5*100*64 bf16
    int i2 = idx - 197888;
    ztabh[i2] = ngnn97_f2bf(ztab[i2]);
  }
}

// ---------------- CSR build ----------------
__global__ __launch_bounds__(256) void ngnn97_hist(const int* __restrict__ dst, int* __restrict__ counts) {
  int e = blockIdx.x * 256 + threadIdx.x;
  if (e < EE) atomicAdd(&counts[dst[e]], 1);
}

__global__ __launch_bounds__(256) void ngnn97_red(const int* __restrict__ counts, int* __restrict__ bsum) {
  __shared__ int s[256];
  int t = threadIdx.x, base = blockIdx.x * 1024;
  int v = 0;
#pragma unroll
  for (int i = 0; i < 4; i++) v += counts[base + t + i * 256];
  s[t] = v; __syncthreads();
  for (int o = 128; o > 0; o >>= 1) { if (t < o) s[t] += s[t + o]; __syncthreads(); }
  if (t == 0) bsum[blockIdx.x] = s[0];
}

__global__ __launch_bounds__(512) void ngnn97_scan1(const int* __restrict__ bsum, int* __restrict__ boff) {
  __shared__ int s[512];
  int t = threadIdx.x;
  int v = (t < NBLK) ? bsum[t] : 0;
  s[t] = v; __syncthreads();
  for (int o = 1; o < 512; o <<= 1) {
    int a = (t >= o) ? s[t - o] : 0;
    __syncthreads(); s[t] += a; __syncthreads();
  }
  if (t < NBLK) boff[t] = s[t] - v;   // exclusive
}

__global__ __launch_bounds__(256) void ngnn97_scan2(const int* __restrict__ counts, const int* __restrict__ boff,
                                                    int* __restrict__ row_ptr, int* __restrict__ cursor) {
  __shared__ int s[256];
  int t = threadIdx.x, base = blockIdx.x * 1024;
  int4 c = *(const int4*)(counts + base + t * 4);
  int tsum = c.x + c.y + c.z + c.w;
  s[t] = tsum; __syncthreads();
  for (int o = 1; o < 256; o <<= 1) {
    int a = (t >= o) ? s[t - o] : 0;
    __syncthreads(); s[t] += a; __syncthreads();
  }
  int off = boff[blockIdx.x] + s[t] - tsum;
  int4 r;
  r.x = off; r.y = off + c.x; r.z = off + c.x + c.y; r.w = off + c.x + c.y + c.z;
  *(int4*)(row_ptr + base + t * 4) = r;
  *(int4*)(cursor + base + t * 4) = r;
}

__global__ __launch_bounds__(256) void ngnn97_fill(const int* __restrict__ src, const int* __restrict__ dst,
                                                   int* __restrict__ cursor, int* __restrict__ srcs) {
  int e = blockIdx.x * 256 + threadIdx.x;
  if (e < EE) {
    int pos = atomicAdd(&cursor[dst[e]], 1);
    srcs[pos] = src[e];
  }
}

// ---------------- node -> graph id precompute (uint8) ----------------
__global__ __launch_bounds__(256) void ngnn97_g8(const int* __restrict__ n2s, const int* __restrict__ s2g,
                                                 unsigned char* __restrict__ g8) {
  int idx = blockIdx.x * 256 + threadIdx.x;
  if (idx < NN) g8[idx] = (unsigned char)s2g[n2s[idx]];
}

// ---------------- bucket nodes by graph: LDS hist + two-pass fill ----------------
__global__ __launch_bounds__(256) void ngnn97_bucket(const unsigned char* __restrict__ g8,
                                                     int* __restrict__ gcur, int* __restrict__ nlist) {
  __shared__ int hcnt[64];
  __shared__ int hbase[64];
  int t = threadIdx.x;
  int base = blockIdx.x * 1024;
  if (t < 64) hcnt[t] = 0;
  __syncthreads();
#pragma unroll
  for (int i = 0; i < 4; i++) {
    int node = base + i * 256 + t;
    if (node < NN) atomicAdd(&hcnt[g8[node]], 1);
  }
  __syncthreads();
  if (t < 64) {
    int c = hcnt[t];
    hbase[t] = (c > 0) ? atomicAdd(&gcur[t], c) : 0;
    hcnt[t] = 0;
  }
  __syncthreads();
#pragma unroll
  for (int i = 0; i < 4; i++) {
    int node = base + i * 256 + t;
    if (node < NN) {
      int g = g8[node];
      int loc = atomicAdd(&hcnt[g], 1);
      int pos = hbase[g] + loc;
      if (pos < GCAP) nlist[g * GCAP + pos] = node;
    }
  }
}

// ---------------- degree-sort: counting sort of nodes by CSR in-degree ----------------
// Uniform-degree waves: gather serial time = avg (not max) chain, no masked-VALU waste.
__global__ __launch_bounds__(256) void ngnn97_dhist(const int* __restrict__ rowp, int* __restrict__ dbins) {
  __shared__ int h[64];
  int t = threadIdx.x, base = blockIdx.x * 1024;
  if (t < 64) h[t] = 0;
  __syncthreads();
#pragma unroll
  for (int i = 0; i < 4; i++) {
    int node = base + i * 256 + t;
    if (node < NN) {
      int d = rowp[node + 1] - rowp[node];
      if (d > 63) d = 63;
      atomicAdd(&h[d], 1);
    }
  }
  __syncthreads();
  if (t < 64 && h[t]) atomicAdd(&dbins[t], h[t]);
}

__global__ __launch_bounds__(64) void ngnn97_dscan(const int* __restrict__ dbins, int* __restrict__ dcur) {
  __shared__ int s[64];
  int t = threadIdx.x;
  int v = dbins[t];
  s[t] = v; __syncthreads();
  for (int o = 1; o < 64; o <<= 1) {
    int a = (t >= o) ? s[t - o] : 0;
    __syncthreads(); s[t] += a; __syncthreads();
  }
  dcur[t] = s[t] - v;   // exclusive prefix
}

__global__ __launch_bounds__(256) void ngnn97_dfill(const int* __restrict__ rowp, int* __restrict__ dcur,
                                                    int* __restrict__ perm) {
  __shared__ int hcnt[64];
  __shared__ int hbase[64];
  int t = threadIdx.x, base = blockIdx.x * 1024;
  if (t < 64) hcnt[t] = 0;
  __syncthreads();
#pragma unroll
  for (int i = 0; i < 4; i++) {
    int node = base + i * 256 + t;
    if (node < NN) {
      int d = rowp[node + 1] - rowp[node];
      if (d > 63) d = 63;
      atomicAdd(&hcnt[d], 1);
    }
  }
  __syncthreads();
  if (t < 64) {
    int c = hcnt[t];
    hbase[t] = (c > 0) ? atomicAdd(&dcur[t], c) : 0;
    hcnt[t] = 0;
  }
  __syncthreads();
#pragma unroll
  for (int i = 0; i < 4; i++) {
    int node = base + i * 256 + t;
    if (node < NN) {
      int d = rowp[node + 1] - rowp[node];
      if (d > 63) d = 63;
      int loc = atomicAdd(&hcnt[d], 1);
      perm[hbase[d] + loc] = node;
    }
  }
}

// ---------------- layer-0 embedding: bf16x8 row copies from ztabh ----------------
__global__ __launch_bounds__(256) void ngnn97_embed(const int* __restrict__ z,
                                                    const unsigned short* __restrict__ ztabh,
                                                    unsigned short* __restrict__ xh) {
  int idx = blockIdx.x * 256 + threadIdx.x;
  int node = idx >> 3, sub = idx & 7;
  if (node < NN) {
    int zz = z[node];
    *(bf16x8*)(xh + (size_t)node * 64 + sub * 8) =
        *(const bf16x8*)(ztabh + zz * 64 + sub * 8);
  }
}

// ---------------- FUSED gather + GRU via MFMA (+ optional transform) ----------------
// FINAL (r7 config, empirically best across 10 rounds: 1066 us):
//  - 1-wave blocks (64 thr) owning 32 ASCENDING degree-sorted nodes; zero barriers;
//    4.7 KB LDS; natural ~60 VGPR -> 4 waves/SIMD (VGPR ladder + wg-slot limit agree).
//  - Falsified alternatives: gather split (r1), forced-occupancy bounds (r2/r5/r6:
//    spill), node-split (r4), srcs prefetch (r9), segment sort (r9), hub-first (r10).
__global__ __launch_bounds__(64, 4) void ngnn97_gru(
    const unsigned short* __restrict__ xh_old, unsigned short* __restrict__ xh_new,
    const int* __restrict__ rowp, const int* __restrict__ srcs,
    const int* __restrict__ perm,
    const unsigned short* __restrict__ Ubt, const float* __restrict__ Ub,
    const unsigned short* __restrict__ Vbt, const float* __restrict__ tfb,
    const int* __restrict__ z, const unsigned short* __restrict__ ztabh,
    int do_transform) {
  __shared__ unsigned short Abuf[32 * 72];     // 4.6 KB: agg -> xh -> xn scratch
  __shared__ int pnode[32];
  const int lane = threadIdx.x;                // 1 wave
  const int ncol = lane & 15, quad = lane >> 4;
  const int nbase = blockIdx.x * 32;

  if (lane < 32) {
    int idx = nbase + lane;
    pnode[lane] = (idx < NN) ? perm[idx] : NN;  // sentinel NN = inactive row
  }
  // same-wave DS ordering: all later reads see these writes

  // ---- gather: 2 sub-batches x 16 rows, 4 lanes (sub) per row -> Abuf cols 0..63 ----
  {
    int grp = lane >> 2, sub = lane & 3;       // grp 0..15; sub owns elems [sub*16,+16)
#pragma unroll
    for (int sb = 0; sb < 2; sb++) {
      int row = sb * 16 + grp;
      int node = pnode[row];
      float lo[8], hi[8];
#pragma unroll
      for (int i = 0; i < 8; i++) { lo[i] = 0.f; hi[i] = 0.f; }
      if (node < NN) {
        int b = rowp[node], e = rowp[node + 1];
        int p = b;
        for (; p + 2 <= e; p += 2) {
          int s0 = srcs[p], s1 = srcs[p + 1];
          const unsigned short* r0 = xh_old + (size_t)s0 * 64 + sub * 16;
          const unsigned short* r1 = xh_old + (size_t)s1 * 64 + sub * 16;
          uint4 u0 = *(const uint4*)(r0);
          uint4 u1 = *(const uint4*)(r0 + 8);
          uint4 u2 = *(const uint4*)(r1);
          uint4 u3 = *(const uint4*)(r1 + 8);
          ngnn97_acc8(u0, lo, hi); ngnn97_acc8(u1, lo + 4, hi + 4);
          ngnn97_acc8(u2, lo, hi); ngnn97_acc8(u3, lo + 4, hi + 4);
        }
        if (p < e) {
          const unsigned short* r0 = xh_old + (size_t)srcs[p] * 64 + sub * 16;
          uint4 u0 = *(const uint4*)(r0);
          uint4 u1 = *(const uint4*)(r0 + 8);
          ngnn97_acc8(u0, lo, hi);
          ngnn97_acc8(u1, lo + 4, hi + 4);
        }
      }
      // pack: dword j of chunk c -> elements (c*8+2j, c*8+2j+1) = (lo, hi)
#pragma unroll
      for (int c = 0; c < 2; c++) {
        bf16x8 ov;
#pragma unroll
        for (int j = 0; j < 4; j++) {
          ov[2 * j]     = (short)ngnn97_f2bf(lo[c * 4 + j]);
          ov[2 * j + 1] = (short)ngnn97_f2bf(hi[c * 4 + j]);
        }
        *(bf16x8*)(Abuf + row * 72 + sub * 16 + c * 8) = ov;
      }
    }
  }

  // ---- afrA frags from gathered agg (same-wave DS ordering: reads after own writes) ----
  bf16x8 afrA[2][2];
#pragma unroll
  for (int mm = 0; mm < 2; mm++)
#pragma unroll
    for (int kc = 0; kc < 2; kc++)
      afrA[mm][kc] = *(const bf16x8*)(Abuf + (mm * 16 + ncol) * 72 + quad * 8 + kc * 32);

  // ---- stage xh_old perm rows -> Abuf cols 0..63 (overwrite agg; in-order DS pipe) ----
#pragma unroll
  for (int i = 0; i < 8; i++) {
    int chunk = i * 64 + lane;                 // 512 = 32 rows x 16 ushort4
    int r2 = chunk >> 4, c4 = (chunk & 15) << 2;
    int node = pnode[r2];
    ushort4 qx = make_ushort4(0, 0, 0, 0);
    if (node < NN) qx = *(const ushort4*)(xh_old + (size_t)node * 64 + c4);
    *(ushort4*)(Abuf + r2 * 72 + c4) = qx;
  }

  bf16x8 afrX[2][2];
#pragma unroll
  for (int mm = 0; mm < 2; mm++)
#pragma unroll
    for (int kc = 0; kc < 2; kc++)
      afrX[mm][kc] = *(const bf16x8*)(Abuf + (mm * 16 + ncol) * 72 + quad * 8 + kc * 32);

  // ---- gate GEMM + GRU update; xn overwrites Abuf cols 0..63 ----
#pragma unroll
  for (int c = 0; c < 4; c++) {
    f32x4 aR[2], aZ[2], aN[2], aH[2];
#pragma unroll
    for (int mm = 0; mm < 2; mm++) {
      aR[mm] = (f32x4){0.f, 0.f, 0.f, 0.f}; aZ[mm] = aR[mm];
      aN[mm] = aR[mm]; aH[mm] = aR[mm];
    }
#pragma unroll
    for (int kc = 0; kc < 4; kc++) {
      const unsigned short* ub = Ubt + (size_t)(c * 16 + ncol) * 128 + quad * 8 + kc * 32;
      bf16x8 bR = *(const bf16x8*)(ub);
      bf16x8 bZ = *(const bf16x8*)(ub + 64 * 128);
      bf16x8 bX = (kc < 2) ? *(const bf16x8*)(ub + 128 * 128)
                           : *(const bf16x8*)(ub + 192 * 128);
#pragma unroll
      for (int mm = 0; mm < 2; mm++) {
        bf16x8 a = (kc < 2) ? afrA[mm][kc] : afrX[mm][kc - 2];
        aR[mm] = __builtin_amdgcn_mfma_f32_16x16x32_bf16(a, bR, aR[mm], 0, 0, 0);
        aZ[mm] = __builtin_amdgcn_mfma_f32_16x16x32_bf16(a, bZ, aZ[mm], 0, 0, 0);
        if (kc < 2) aN[mm] = __builtin_amdgcn_mfma_f32_16x16x32_bf16(a, bX, aN[mm], 0, 0, 0);
        else        aH[mm] = __builtin_amdgcn_mfma_f32_16x16x32_bf16(a, bX, aH[mm], 0, 0, 0);
      }
    }
    int j = c * 16 + ncol;
    float bRs = Ub[j], bZs = Ub[64 + j], bNs = Ub[128 + j], bHs = Ub[192 + j];
#pragma unroll
    for (int mm = 0; mm < 2; mm++)
#pragma unroll
      for (int r = 0; r < 4; r++) {
        int row = mm * 16 + quad * 4 + r;
        float R = aR[mm][r] + bRs, Z = aZ[mm][r] + bZs;
        float Nv = aN[mm][r] + bNs, H = aH[mm][r] + bHs;
        float rg = 1.f / (1.f + __expf(-R));
        float ug = 1.f / (1.f + __expf(-Z));
        float e2 = __expf(2.f * (Nv + rg * H));
        float nn2 = 1.f - 2.f / (e2 + 1.f);    // tanh via fast exp (saturates safely)
        float xo = ngnn97_bf2f(Abuf[row * 72 + j]);   // xh staged in cols 0..63
        Abuf[row * 72 + j] = ngnn97_f2bf((1.f - ug) * nn2 + ug * xo);
      }
  }

  if (do_transform) {
    // ---- A2-frags: xn from LDS, ze direct from bf16 ztab ----
    bf16x8 afrN[2][2], afrE[2][2];
#pragma unroll
    for (int mm = 0; mm < 2; mm++) {
      int node = pnode[mm * 16 + ncol];
      int zz = (node < NN) ? z[node] : 0;
#pragma unroll
      for (int kc = 0; kc < 2; kc++) {
        afrN[mm][kc] = *(const bf16x8*)(Abuf + (mm * 16 + ncol) * 72 + quad * 8 + kc * 32);
        afrE[mm][kc] = *(const bf16x8*)(ztabh + zz * 64 + quad * 8 + kc * 32);
      }
    }
    // ---- transform GEMM -> Abuf cols 0..63 ----
#pragma unroll
    for (int c2 = 0; c2 < 4; c2++) {
      f32x4 acc[2];
      acc[0] = (f32x4){0.f, 0.f, 0.f, 0.f}; acc[1] = acc[0];
#pragma unroll
      for (int kc = 0; kc < 4; kc++) {
        bf16x8 bV = *(const bf16x8*)(Vbt + (size_t)(c2 * 16 + ncol) * 128 + quad * 8 + kc * 32);
#pragma unroll
        for (int mm = 0; mm < 2; mm++) {
          bf16x8 a = (kc < 2) ? afrN[mm][kc] : afrE[mm][kc - 2];
          acc[mm] = __builtin_amdgcn_mfma_f32_16x16x32_bf16(a, bV, acc[mm], 0, 0, 0);
        }
      }
      int j = c2 * 16 + ncol;
      float bt = tfb[j];
#pragma unroll
      for (int mm = 0; mm < 2; mm++)
#pragma unroll
        for (int r = 0; r < 4; r++) {
          int row = mm * 16 + quad * 4 + r;
          Abuf[row * 72 + j] = ngnn97_f2bf(acc[mm][r] + bt);
        }
    }
  }

  // ---- store: Abuf cols 0..63 -> xh_new[perm rows] (128B segments per row) ----
#pragma unroll
  for (int i = 0; i < 8; i++) {
    int chunk = i * 64 + lane;
    int r2 = chunk >> 4, c4 = (chunk & 15) << 2;
    int node = pnode[r2];
    if (node < NN)
      *(ushort4*)(xh_new + (size_t)node * 64 + c4) = *(const ushort4*)(Abuf + r2 * 72 + c4);
  }
}

// ---------------- pooling: bucketed contiguous reduction ----------------
__global__ __launch_bounds__(256) void ngnn97_pool(const unsigned short* __restrict__ xh,
                                                   const int* __restrict__ nlist,
                                                   const int* __restrict__ gcur,
                                                   float* __restrict__ gpool) {
  __shared__ float part[4][64];
  int t = threadIdx.x;
  int lane = t & 63, wv = t >> 6;
  int g = blockIdx.x >> 4, c = blockIdx.x & 15;
  int cnt = gcur[g];
  if (cnt > GCAP) cnt = GCAP;
  int r0 = (c * cnt) >> 4, r1 = ((c + 1) * cnt) >> 4;
  const int* nl = nlist + g * GCAP;
  float a0 = 0.f, a1 = 0.f;
  int r = r0 + wv;
  for (; r + 4 < r1; r += 8) {
    int n0 = nl[r], n1 = nl[r + 4];
    a0 += ngnn97_bf2f(xh[(size_t)n0 * 64 + lane]);
    a1 += ngnn97_bf2f(xh[(size_t)n1 * 64 + lane]);
  }
  if (r < r1) a0 += ngnn97_bf2f(xh[(size_t)nl[r] * 64 + lane]);
  part[wv][lane] = a0 + a1;
  __syncthreads();
  if (t < 64)
    atomicAdd(&gpool[g * 64 + t], part[0][t] + part[1][t] + part[2][t] + part[3][t]);
}

// ---------------- MLP head (output: float32 [G,1]) ----------------
__global__ __launch_bounds__(256) void ngnn97_head(
    const float* __restrict__ gpool,
    const float* __restrict__ W1, const float* __restrict__ b1,
    const float* __restrict__ W2, const float* __restrict__ b2,
    const float* __restrict__ W3, const float* __restrict__ b3,
    float* __restrict__ out) {
  __shared__ float gp[4096];
  __shared__ float h1[2048];
  __shared__ float h2[1024];
  int t = threadIdx.x;
  for (int i = t; i < 4096; i += 256) gp[i] = gpool[i];
  __syncthreads();
  for (int i = t; i < 2048; i += 256) {
    int g = i >> 5, o = i & 31;
    float a = b1[o];
    for (int d = 0; d < 64; d++) a = fmaf(gp[g * 64 + d], W1[o * 64 + d], a);
    h1[i] = (a > 0.f) ? a : (__expf(a) - 1.f);
  }
  __syncthreads();
  for (int i = t; i < 1024; i += 256) {
    int g = i >> 4, o = i & 15;
    float a = b2[o];
    for (int d = 0; d < 32; d++) a = fmaf(h1[g * 32 + d], W2[o * 32 + d], a);
    h2[i] = (a > 0.f) ? a : (__expf(a) - 1.f);
  }
  __syncthreads();
  if (t < 64) {
    float a = b3[0];
    for (int d = 0; d < 16; d++) a = fmaf(h2[t * 16 + d], W3[d], a);
    out[t] = a;
  }
}

// ---------------- workspace layout (byte offsets) ----------------
#define OFF_XH0   ((size_t)0)                          // N*64 bf16 = 64,000,000
#define OFF_XH1   ((size_t)64000000)                   // N*64 bf16 = 64,000,000
#define OFF_CNT   ((size_t)128000000)                  // NP int
#define OFF_ROW   (OFF_CNT + (size_t)NP * 4)
#define OFF_CUR   (OFF_ROW + (size_t)NP * 4)
#define OFF_SRC   (OFF_CUR + (size_t)NP * 4)           // E int
#define OFF_BSUM  (OFF_SRC + (size_t)EE * 4)
#define OFF_BOFF  (OFF_BSUM + (size_t)2048)
#define OFF_U     (OFF_BOFF + (size_t)2048)            // Ubt bf16 5*256*128
#define OFF_UB    (OFF_U + (size_t)327680)             // Ub f32 5*256
#define OFF_V     (OFF_UB + (size_t)5120)              // Vbt bf16 4*64*128
#define OFF_GP    (OFF_V + (size_t)65536)              // gpool 64*64 f32
#define OFF_G8    (OFF_GP + (size_t)16384)             // N uint8 (padded)
#define OFF_ZTH   (OFF_G8 + (size_t)500736)            // ztabh bf16 5*100*64
#define OFF_GCUR  (OFF_ZTH + (size_t)64000)            // 64 ints (+pad)
#define OFF_NL    (OFF_GCUR + (size_t)1024)            // nlist 64*GCAP ints = 4 MB
#define OFF_PERM  (OFF_NL + (size_t)64 * GCAP * 4)     // degree-sorted node perm, NP ints
#define OFF_DB    (OFF_PERM + (size_t)NP * 4)          // degree bins, 64 ints
#define OFF_DC    (OFF_DB + (size_t)256)               // degree cursors, 64 ints
#define WS_NEED   (OFF_DC + (size_t)256)               // ~= 146.2 MB (proven budget 203.8)

extern "C" void kernel_launch(void* const* d_in, const int* in_sizes, int n_in,
                              void* d_out, int out_size, void* d_ws, size_t ws_size,
                              hipStream_t stream) {
  float* out = (float*)d_out;   // reference output is float32 [G,1]
  if (ws_size < WS_NEED) {
    ngnn97_code<<<1, 64, 0, stream>>>(out, 7.0f);
    return;
  }

  const int* z    = (const int*)d_in[0];
  const int* ei   = (const int*)d_in[1];
  const int* n2s  = (const int*)d_in[2];
  const int* s2g  = (const int*)d_in[3];
  const float* ztab = (const float*)d_in[4];
  const float* tfW  = (const float*)d_in[5];
  const float* tfb  = (const float*)d_in[6];
  const float* ggc  = (const float*)d_in[7];
  const float* wih  = (const float*)d_in[8];
  const float* whh  = (const float*)d_in[9];
  const float* bih  = (const float*)d_in[10];
  const float* bhh  = (const float*)d_in[11];
  const float* W1   = (const float*)d_in[12];
  const float* b1   = (const float*)d_in[13];
  const float* W2   = (const float*)d_in[14];
  const float* b2   = (const float*)d_in[15];
  const float* W3   = (const float*)d_in[16];
  const float* b3   = (const float*)d_in[17];

  char* ws = (char*)d_ws;
  unsigned short* xh0    = (unsigned short*)(ws + OFF_XH0);
  unsigned short* xh1    = (unsigned short*)(ws + OFF_XH1);
  int*            counts = (int*)(ws + OFF_CNT);
  int*            rowp   = (int*)(ws + OFF_ROW);
  int*            curs   = (int*)(ws + OFF_CUR);
  int*            srcs   = (int*)(ws + OFF_SRC);
  int*            bsum   = (int*)(ws + OFF_BSUM);
  int*            boff   = (int*)(ws + OFF_BOFF);
  unsigned short* Ubt    = (unsigned short*)(ws + OFF_U);
  float*          Ub     = (float*)(ws + OFF_UB);
  unsigned short* Vbt    = (unsigned short*)(ws + OFF_V);
  float*          gpool  = (float*)(ws + OFF_GP);
  unsigned char*  g8     = (unsigned char*)(ws + OFF_G8);
  unsigned short* ztabh  = (unsigned short*)(ws + OFF_ZTH);
  int*            gcur   = (int*)(ws + OFF_GCUR);
  int*            nlist  = (int*)(ws + OFF_NL);
  int*            perm   = (int*)(ws + OFF_PERM);
  int*            dbins  = (int*)(ws + OFF_DB);
  int*            dcur   = (int*)(ws + OFF_DC);

  hipMemsetAsync(counts, 0, (size_t)NP * 4, stream);
  hipMemsetAsync(gpool, 0, 16384, stream);
  hipMemsetAsync(gcur, 0, 1024, stream);
  hipMemsetAsync(dbins, 0, 256, stream);

  ngnn97_pre<<<899, 256, 0, stream>>>(ggc, wih, whh, bih, bhh, tfW, ztab, Ubt, Ub, Vbt, ztabh);
  ngnn97_g8<<<(NN + 255) / 256, 256, 0, stream>>>(n2s, s2g, g8);
  ngnn97_bucket<<<NBLK, 256, 0, stream>>>(g8, gcur, nlist);

  // CSR by dst
  const int* srcp = ei;
  const int* dstp = ei + EE;
  ngnn97_hist<<<(EE + 255) / 256, 256, 0, stream>>>(dstp, counts);
  ngnn97_red<<<NBLK, 256, 0, stream>>>(counts, bsum);
  ngnn97_scan1<<<1, 512, 0, stream>>>(bsum, boff);
  ngnn97_scan2<<<NBLK, 256, 0, stream>>>(counts, boff, rowp, curs);
  ngnn97_fill<<<(EE + 255) / 256, 256, 0, stream>>>(srcp, dstp, curs, srcs);
  // rowp[n]..rowp[n+1] bounds node n's incoming-edge list

  // degree-sorted permutation (counting sort, 64 bins)
  ngnn97_dhist<<<NBLK, 256, 0, stream>>>(rowp, dbins);
  ngnn97_dscan<<<1, 64, 0, stream>>>(dbins, dcur);
  ngnn97_dfill<<<NBLK, 256, 0, stream>>>(rowp, dcur, perm);

  ngnn97_embed<<<(NN * 8 + 255) / 256, 256, 0, stream>>>(z, ztabh, xh0);

  unsigned short* xc = xh0;
  unsigned short* xn2 = xh1;
  for (int l = 0; l < 5; l++) {
    ngnn97_gru<<<(NN + 31) / 32, 64, 0, stream>>>(
        xc, xn2, rowp, srcs, perm,
        Ubt + (size_t)l * 32768, Ub + (size_t)l * 256,
        Vbt + (size_t)(l < 4 ? l : 0) * 8192, tfb + (size_t)(l < 4 ? l : 0) * 64,
        z, ztabh + (size_t)(l < 4 ? l + 1 : 0) * 6400, (l < 4) ? 1 : 0);
    unsigned short* tmp = xc; xc = xn2; xn2 = tmp;
  }
  // final state in xc

  ngnn97_pool<<<1024, 256, 0, stream>>>(xc, nlist, gcur, gpool);
  ngnn97_head<<<1, 256, 0, stream>>>(gpool, W1, b1, W2, b2, W3, b3, out);
}